// Round 12
// baseline (830.236 us; speedup 1.0000x reference)
//
#include <hip/hip_runtime.h>
#include <cstdint>
#include <cstddef>

// Problem constants
#define NUM_C 4096
#define BB 32
#define TT 512
#define DD 128
#define MM 50

using ull = unsigned long long;

__device__ __forceinline__ float sigmoidf_(float x){ return 1.0f/(1.0f + expf(-x)); }

// Fast transcendentals on the serial critical path: v_exp_f32 / v_rcp_f32
__device__ __forceinline__ float fexp2_(float x){ return __builtin_amdgcn_exp2f(x); }
__device__ __forceinline__ float frcp_(float x){ return __builtin_amdgcn_rcpf(x); }
__device__ __forceinline__ float fast_sig_(float x){
  return frcp_(1.0f + fexp2_(-1.44269504088896341f*x));
}
__device__ __forceinline__ float fast_tanh_(float x){
  float t = fexp2_(2.88539008177792681f*x);     // e^(2x)
  return 1.0f - 2.0f*frcp_(t + 1.0f);
}

// Quad reduction via DPP (VALU pipe, no LDS): sum over lanes {x, x^1, x^2, x^3}
__device__ __forceinline__ float quadSum_(float v){
  int t = __builtin_amdgcn_update_dpp(0, __float_as_int(v), 0xB1, 0xF, 0xF, true);
  v += __int_as_float(t);
  t = __builtin_amdgcn_update_dpp(0, __float_as_int(v), 0x4E, 0xF, 0xF, true);
  v += __int_as_float(t);
  return v;
}

// Relaxed barrier: LDS visibility only (no vmcnt/expcnt drain).
__device__ __forceinline__ void barL_(){
  asm volatile("s_waitcnt lgkmcnt(0)\n\ts_barrier" ::: "memory");
}
// Drain this thread's outstanding vector-memory ops.
__device__ __forceinline__ void waitVM_(){
  asm volatile("s_waitcnt vmcnt(0)" ::: "memory");
}

__device__ __forceinline__ float agLoad_(const float* p){
  return __hip_atomic_load(p, __ATOMIC_RELAXED, __HIP_MEMORY_SCOPE_AGENT);
}
__device__ __forceinline__ void agStore_(float* p, float v){
  __hip_atomic_store(p, v, __ATOMIC_RELAXED, __HIP_MEMORY_SCOPE_AGENT);
}

// ---------------------------------------------------------------------------
// Kernel A (R16): parallel precompute + (by==32) one-time init:
//   - blocks (bx, 0..31): original kPre body (unchanged arithmetic)
//   - blocks (bx, 32):    Ge/Ga weight products (kWW math, d = bx*8..+8),
//                         Wih4 repack, and pipeline-flag zeroing (bx==0).
// ---------------------------------------------------------------------------
__global__ __launch_bounds__(256) void kPre(
    const int* __restrict__ q, const int* __restrict__ r,
    const float* __restrict__ k_emb, const float* __restrict__ Mk,
    const float* __restrict__ f_W, const float* __restrict__ f_b,
    const float* __restrict__ a_W, const float* __restrict__ a_b,
    float* __restrict__ wAll, ull* __restrict__ keyLo, ull* __restrict__ keyHi,
    float* __restrict__ fpre, float* __restrict__ ypre,
    const float* __restrict__ e_W, const float* __restrict__ add_W,
    float* __restrict__ Ge, float* __restrict__ Ga,
    const float* __restrict__ Wih, float* __restrict__ Wih4,
    int* __restrict__ prog)
{
  const int b = blockIdx.y, t0 = blockIdx.x * 32, tid = threadIdx.x;
  __shared__ __align__(16) float sK[32*129];
  __shared__ int sQ[32];
  __shared__ int sR[32];
  __shared__ union UU {
    struct { float sMk[MM*129]; double sZ[32*MM]; } p2;
    float sW2[128*65];
  } u;

  if (b == 32){
    // ---------------- init path ----------------
    const int bx = blockIdx.x;
    if (bx == 0 && tid < 96) prog[tid] = 0;     // pipeline flags
    // stage e_W/add_W rows d = bx*8 .. bx*8+7 into sK
    for (int i = tid; i < 8*128; i += 256){
      int ld = i >> 7, j = i & 127;
      sK[i]        = e_W  [(size_t)(bx*8 + ld)*DD + j];
      sK[1024 + i] = add_W[(size_t)(bx*8 + ld)*DD + j];
    }
    __syncthreads();
    {
      const int ld = tid >> 5, lane = tid & 31;
      const int d = bx*8 + ld;
      float ge[4] = {0.f,0.f,0.f,0.f}, ga[4] = {0.f,0.f,0.f,0.f};
      for (int j = 0; j < 128; j++){
        float sej = sK[ld*128 + j], saj = sK[1024 + ld*128 + j];
        #pragma unroll
        for (int uu = 0; uu < 4; uu++){
          float af = a_W[(size_t)j*(NUM_C + DD) + NUM_C + lane + 32*uu];
          ge[uu] += sej*af;
          ga[uu] += saj*af;
        }
      }
      #pragma unroll
      for (int uu = 0; uu < 4; uu++){
        Ge[(size_t)d*DD + lane + 32*uu] = ge[uu];
        Ga[(size_t)d*DD + lane + 32*uu] = ga[uu];
      }
    }
    // Wih4 repack: this block handles idx bx*4096 .. +4095
    for (int i = tid; i < 4096; i += 256){
      int idx = bx*4096 + i;
      int j = idx >> 7, k = idx & 127;
      Wih4[(size_t)(k >> 2)*2048 + j*4 + (k & 3)] = Wih[idx];
    }
    return;
  }

  // ---------------- original kPre body ----------------
  if (tid < 32){ sQ[tid] = q[b*TT + t0 + tid]; sR[tid] = r[b*TT + t0 + tid]; }
  __syncthreads();
  for (int i = tid; i < 32*128; i += 256){
    int tl = i >> 7, j = i & 127;
    sK[tl*129 + j] = k_emb[(size_t)sQ[tl]*DD + j];
  }
  for (int i = tid; i < MM*128; i += 256){
    int m = i >> 7, j = i & 127;
    u.p2.sMk[m*129 + j] = Mk[i];
  }
  __syncthreads();

  for (int idx = tid; idx < 32*MM; idx += 256){
    int tl = idx / MM, m = idx - tl*MM;
    double z = 0.0;
    for (int j = 0; j < DD; j++)
      z += (double)sK[tl*129 + j] * (double)u.p2.sMk[m*129 + j];
    u.p2.sZ[tl*MM + m] = z;
  }
  __syncthreads();

  {
    int tl = tid >> 3, l8 = tid & 7;
    double zmax = -1e300;
    for (int m = l8; m < MM; m += 8) zmax = fmax(zmax, u.p2.sZ[tl*MM + m]);
    for (int s = 1; s < 8; s <<= 1) zmax = fmax(zmax, __shfl_xor(zmax, s));
    double se = 0.0;
    for (int m = l8; m < MM; m += 8){
      double e = exp(u.p2.sZ[tl*MM + m] - zmax);
      u.p2.sZ[tl*MM + m] = e;
      se += e;
    }
    for (int s = 1; s < 8; s <<= 1) se += __shfl_xor(se, s);
    double inv = 1.0 / se;
    ull klo = 0, khi = 0;
    for (int m = l8; m < MM; m += 8){
      double w = u.p2.sZ[tl*MM + m] * inv;
      wAll[((size_t)(b*TT + t0 + tl))*MM + m] = (float)w;
      double tw = fmin((w - 0.075)/(0.088 - 0.075), (1.0 - w)/(1.0 - 0.088));
      tw = fmax(tw, 0.0);
      ull iv = (tw >= 0.6) ? 2ull : ((tw >= 0.1) ? 1ull : 0ull);
      if (m < 32) klo |= iv << (2*m); else khi |= iv << (2*(m-32));
    }
    for (int s = 1; s < 8; s <<= 1){ klo |= __shfl_xor(klo, s); khi |= __shfl_xor(khi, s); }
    if (l8 == 0){ keyLo[b*TT + t0 + tl] = klo; keyHi[b*TT + t0 + tl] = khi; }
  }

  {
    const int dq = tid & 31, tq = tid >> 5;
    float acc[4][4];
    #pragma unroll
    for (int a = 0; a < 4; a++){ acc[a][0]=0.f; acc[a][1]=0.f; acc[a][2]=0.f; acc[a][3]=0.f; }
    for (int jh = 0; jh < 2; jh++){
      __syncthreads();
      for (int i = tid; i < 128*64; i += 256){
        int dd = i >> 6, jj = i & 63;
        u.sW2[dd*65 + jj] = f_W[dd*256 + 128 + jh*64 + jj];
      }
      __syncthreads();
      for (int jj = 0; jj < 64; jj++){
        float kv[4], wv[4];
        #pragma unroll
        for (int a = 0; a < 4; a++) kv[a] = sK[(tq*4 + a)*129 + jh*64 + jj];
        #pragma unroll
        for (int c = 0; c < 4; c++) wv[c] = u.sW2[(dq*4 + c)*65 + jj];
        #pragma unroll
        for (int a = 0; a < 4; a++){
          acc[a][0] += kv[a]*wv[0]; acc[a][1] += kv[a]*wv[1];
          acc[a][2] += kv[a]*wv[2]; acc[a][3] += kv[a]*wv[3];
        }
      }
    }
    #pragma unroll
    for (int a = 0; a < 4; a++){
      int tl = tq*4 + a;
      #pragma unroll
      for (int c = 0; c < 4; c++){
        int d = dq*4 + c;
        fpre[((size_t)(b*TT + t0 + tl))*DD + d] = acc[a][c] + f_b[d];
      }
    }
  }

  for (int i = tid; i < 32*DD; i += 256){
    int tl = i >> 7, d = i & 127;
    ypre[((size_t)(b*TT + t0 + tl))*DD + d] =
        a_W[(size_t)d*(NUM_C + DD) + sQ[tl]] * (float)sR[tl] + a_b[d];
  }
}

// ---------------------------------------------------------------------------
// Kernel F (R16): 4-role fused pipeline (128 blocks, all co-resident).
//   Blocks  96..127: eapre role — per chunk: stage 8 ypre rows, compute
//                    2048 eapre vals (kEA-identical k-ascending order),
//                    agent-store, flag prog3[b]=ch+1. No waits.
//   Blocks   0..31 : memory recurrence (R11 math). eapre prefetch now
//                    agent loads gated by all-thread spin on prog3.
//   Blocks  32..63 : gates GEMM + kMatch prephase (R15).
//   Blocks  64..95 : LSTM + kOut tail. gbuf staging replaced by per-step
//                    direct agent gp loads with 1-step register prefetch.
// ---------------------------------------------------------------------------
__global__ __launch_bounds__(512, 2) __attribute__((amdgpu_waves_per_eu(2, 2)))
void kFused(
    const float* __restrict__ wAll, const float* __restrict__ fpre,
    float* __restrict__ eapre, const float* __restrict__ f_W,
    const float* __restrict__ Ge, const float* __restrict__ Ga,
    const float* __restrict__ Mv0, float* __restrict__ fAll,
    const float* __restrict__ Wih4, const float* __restrict__ bih,
    const float* __restrict__ bhh, const ull* __restrict__ keyLo,
    const ull* __restrict__ keyHi, int* __restrict__ prevA,
    const float* __restrict__ Whh, float* __restrict__ Hh,
    float* __restrict__ Ch, float* __restrict__ gpre,
    const float* __restrict__ p_W, const float* __restrict__ p_b,
    float* __restrict__ out, int* __restrict__ prog,
    const float* __restrict__ ypre, const float* __restrict__ e_W,
    const float* __restrict__ add_W, const float* __restrict__ e_b,
    const float* __restrict__ add_b)
{
  const int tid = threadIdx.x;
  const int b = blockIdx.x & 31;
  const size_t base = (size_t)b*TT;

  __shared__ __align__(16) union SU {
    struct {
      float bufR[144]; float bufF[144]; float sW9[9*52];
      float sF8[8*128]; float sEA8[8*256]; float fO8[8*128];
    } m;
    struct { float sFc[8*128]; ull slo[TT]; ull shi[TT]; } g;
    struct {
      float xh[2][144]; int spv[TT];
      float hRing[8*128]; float cRing[8*128]; float pw[DD];
    } l;
    struct { float sY[8*128]; } e;
  } su;

  if (blockIdx.x >= 96){
    // ==================== eapre role (kEA math, chunked) ===================
    const int j  = tid & 255;
    const int rg = tid >> 8;        // 0/1: rows rg, rg+2, rg+4, rg+6
    const float* wcol = (j < 128) ? &e_W[(size_t)j*DD] : &add_W[(size_t)(j-128)*DD];
    const float bias  = (j < 128) ? e_b[j] : add_b[j - 128];
    const float4* wcol4 = reinterpret_cast<const float4*>(wcol);

    for (int ch = 0; ch < TT/8; ch++){
      const int t0 = ch*8;
      if (ch) __syncthreads();      // prev chunk's sY reads done
      if (tid < 256){
        float4 v = reinterpret_cast<const float4*>(&ypre[(base + t0)*DD])[tid];
        reinterpret_cast<float4*>(su.e.sY)[tid] = v;
      }
      barL_();
      float acc[4] = {0.f,0.f,0.f,0.f};
      for (int k4 = 0; k4 < 32; k4++){
        float4 w = wcol4[k4];
        #pragma unroll
        for (int uu = 0; uu < 4; uu++){
          const float* y = &su.e.sY[(rg + 2*uu)*128 + k4*4];
          acc[uu] += y[0]*w.x; acc[uu] += y[1]*w.y;
          acc[uu] += y[2]*w.z; acc[uu] += y[3]*w.w;
        }
      }
      #pragma unroll
      for (int uu = 0; uu < 4; uu++)
        agStore_(&eapre[(base + t0 + rg + 2*uu)*256 + j], acc[uu] + bias);
      waitVM_();
      __syncthreads();              // all stores drained
      if (tid == 0)
        __hip_atomic_store(&prog[64 + b], ch + 1, __ATOMIC_RELAXED, __HIP_MEMORY_SCOPE_AGENT);
    }

  } else if (blockIdx.x < 32){
    // ==================== memory-recurrence role ===========================
    const int dd = tid >> 2, kc = tid & 3, m0 = kc*13;
    const int wslot = (dd >> 5)*36 + (dd & 31);

    float mv[13];
    #pragma unroll
    for (int i = 0; i < 13; i++){
      int m = m0 + i;
      mv[i] = (m < MM) ? Mv0[(size_t)m*DD + dd] : 0.f;
    }
    float wf[32], ge[32], ga[32];
    {
      const float4* p;
      p = reinterpret_cast<const float4*>(&f_W[dd*256 + kc*32]);
      #pragma unroll
      for (int i = 0; i < 8; i++){ float4 v = p[i]; wf[4*i]=v.x; wf[4*i+1]=v.y; wf[4*i+2]=v.z; wf[4*i+3]=v.w; }
      p = reinterpret_cast<const float4*>(&Ge[(size_t)dd*DD + kc*32]);
      #pragma unroll
      for (int i = 0; i < 8; i++){ float4 v = p[i]; ge[4*i]=v.x; ge[4*i+1]=v.y; ge[4*i+2]=v.z; ge[4*i+3]=v.w; }
      p = reinterpret_cast<const float4*>(&Ga[(size_t)dd*DD + kc*32]);
      #pragma unroll
      for (int i = 0; i < 8; i++){ float4 v = p[i]; ga[4*i]=v.x; ga[4*i+1]=v.y; ga[4*i+2]=v.z; ga[4*i+3]=v.w; }
    }

    const int rr0 = tid / 50, mm0 = tid - rr0*50;   // valid when tid < 450
    if (tid < 18){ int rr = tid >> 1; su.m.sW9[rr*52 + 50 + (tid & 1)] = 0.f; }

    // register prefetch of chunk 0 (fpre/wAll from kPre: plain loads;
    // eapre from in-kernel role: agent loads after prog3 >= 1)
    float4 pF = {0.f,0.f,0.f,0.f};
    float pEA0 = 0.f, pEA1 = 0.f, pEA2 = 0.f, pEA3 = 0.f;
    float pW = 0.f;
    if (tid < 256) pF = reinterpret_cast<const float4*>(&fpre[base*DD])[tid];
    if (tid < 450) pW = wAll[(base + rr0)*MM + mm0];
    while (__hip_atomic_load(&prog[64 + b], __ATOMIC_ACQUIRE, __HIP_MEMORY_SCOPE_AGENT) < 1)
      __builtin_amdgcn_s_sleep(2);
    {
      const float* ep = &eapre[base*256 + tid*4];
      pEA0 = agLoad_(ep+0); pEA1 = agLoad_(ep+1);
      pEA2 = agLoad_(ep+2); pEA3 = agLoad_(ep+3);
    }

    float wreg[13];

    for (int ch = 0; ch < TT/8; ch++){
      const int t0 = ch*8;
      if (ch){
        if (tid < 256){
          float4 v = reinterpret_cast<const float4*>(su.m.fO8)[tid];
          float* dst = &fAll[(base + t0 - 8)*DD + tid*4];
          agStore_(dst+0, v.x); agStore_(dst+1, v.y);
          agStore_(dst+2, v.z); agStore_(dst+3, v.w);
        }
      }
      if (tid < 256) reinterpret_cast<float4*>(su.m.sF8)[tid] = pF;
      su.m.sEA8[tid*4+0] = pEA0; su.m.sEA8[tid*4+1] = pEA1;
      su.m.sEA8[tid*4+2] = pEA2; su.m.sEA8[tid*4+3] = pEA3;
      if (tid < 450) su.m.sW9[rr0*52 + mm0] = pW;
      if (ch && tid < 256) waitVM_();     // fAll stores complete before flag
      if (t0 + 8 < TT){
        if (tid < 256) pF = reinterpret_cast<const float4*>(&fpre[(base + t0 + 8)*DD])[tid];
        if (tid < 450) pW = (t0 + 8 + rr0 < TT) ? wAll[(base + t0 + 8 + rr0)*MM + mm0] : 0.f;
      }
      barL_();   // R: chunk published (and all fAll stores drained)
      if (ch && tid == 0)
        __hip_atomic_store(&prog[b], ch, __ATOMIC_RELAXED, __HIP_MEMORY_SCOPE_AGENT);

      // eapre prefetch for chunk ch+1 (all-thread spin; hot after chunk ~2)
      if (t0 + 8 < TT){
        while (__hip_atomic_load(&prog[64 + b], __ATOMIC_ACQUIRE, __HIP_MEMORY_SCOPE_AGENT) < ch + 2)
          __builtin_amdgcn_s_sleep(2);
        const float* ep = &eapre[(base + t0 + 8)*256 + tid*4];
        pEA0 = agLoad_(ep+0); pEA1 = agLoad_(ep+1);
        pEA2 = agLoad_(ep+2); pEA3 = agLoad_(ep+3);
      }

      if (ch == 0){
        #pragma unroll
        for (int i = 0; i < 13; i++) wreg[i] = su.m.sW9[m0 + i];
        float rr = 0.f;
        #pragma unroll
        for (int i = 0; i < 13; i++) rr += wreg[i]*mv[i];
        rr = quadSum_(rr);
        if (kc == 0) su.m.bufR[wslot] = rr;
        barL_();
      }

      #pragma unroll
      for (int tc = 0; tc < 8; tc++){
        float wn[13];
        #pragma unroll
        for (int i = 0; i < 13; i++) wn[i] = su.m.sW9[(tc+1)*52 + m0 + i];

        // ---- stage F: f = tanh(read @ f_Wr.T + fpre) ----
        {
          const float4* x4 = reinterpret_cast<const float4*>(&su.m.bufR[kc*36]);
          float a0=0.f,a1=0.f,a2=0.f,a3=0.f;
          #pragma unroll
          for (int i = 0; i < 8; i++){
            float4 xv = x4[i];
            a0 += xv.x*wf[4*i]; a1 += xv.y*wf[4*i+1]; a2 += xv.z*wf[4*i+2]; a3 += xv.w*wf[4*i+3];
          }
          float s = quadSum_((a0+a1)+(a2+a3));
          float fval = fast_tanh_(s + su.m.sF8[tc*128 + dd]);
          if (kc == 0){
            su.m.bufF[wslot] = fval;
            su.m.fO8[tc*128 + dd] = fval;
          }
        }
        barL_();   // B

        // ---- stage EA: e,a from f; mv update; read_{t+1} = wn . mv_new ----
        {
          const float4* x4 = reinterpret_cast<const float4*>(&su.m.bufF[kc*36]);
          float e0=0.f,e1=0.f,g0=0.f,g1=0.f;
          #pragma unroll
          for (int i = 0; i < 8; i++){
            float4 xv = x4[i];
            e0 += xv.x*ge[4*i];   e1 += xv.y*ge[4*i+1];
            e0 += xv.z*ge[4*i+2]; e1 += xv.w*ge[4*i+3];
            g0 += xv.x*ga[4*i];   g1 += xv.y*ga[4*i+1];
            g0 += xv.z*ga[4*i+2]; g1 += xv.w*ga[4*i+3];
          }
          float ep = quadSum_(e0 + e1);
          float ap = quadSum_(g0 + g1);
          float e_d = fast_sig_(ep + su.m.sEA8[tc*256 + dd]);
          float a_d = fast_tanh_(ap + su.m.sEA8[tc*256 + 128 + dd]);
          float rp0 = 0.f, rp1 = 0.f;
          #pragma unroll
          for (int i = 0; i < 13; i++){
            float t = __builtin_fmaf(-e_d, mv[i], a_d);
            mv[i] = __builtin_fmaf(wreg[i], t, mv[i]);
            if (i & 1) rp1 = __builtin_fmaf(wn[i], mv[i], rp1);
            else       rp0 = __builtin_fmaf(wn[i], mv[i], rp0);
          }
          float rd = quadSum_(rp0 + rp1);
          if (kc == 0) su.m.bufR[wslot] = rd;
        }
        #pragma unroll
        for (int i = 0; i < 13; i++) wreg[i] = wn[i];
        barL_();   // C
      }
    }

    // tail: store last chunk + final flag
    if (tid < 256){
      float4 v = reinterpret_cast<const float4*>(su.m.fO8)[tid];
      float* dst = &fAll[(base + TT - 8)*DD + tid*4];
      agStore_(dst+0, v.x); agStore_(dst+1, v.y);
      agStore_(dst+2, v.z); agStore_(dst+3, v.w);
      waitVM_();
    }
    __syncthreads();
    if (tid == 0)
      __hip_atomic_store(&prog[b], TT/8, __ATOMIC_RELAXED, __HIP_MEMORY_SCOPE_AGENT);

  } else if (blockIdx.x < 64){
    // ==================== gates-GEMM role (+ kMatch prephase) ==============
    const float biasj = bih[tid] + bhh[tid];

    {
      su.g.slo[tid] = keyLo[base + tid];
      su.g.shi[tid] = keyHi[base + tid];
      barL_();
      const ull mylo = su.g.slo[tid], myhi = su.g.shi[tid];
      int found = -1;
      for (int j = tid - 1; j >= 0; j--){
        if (su.g.slo[j] == mylo && su.g.shi[j] == myhi){ found = j; break; }
      }
      __hip_atomic_store(&prevA[base + tid], found, __ATOMIC_RELAXED, __HIP_MEMORY_SCOPE_AGENT);
      waitVM_();
    }

    for (int ch = 0; ch < TT/8; ch++){
      const int t0 = ch*8;
      if (tid == 0){
        while (__hip_atomic_load(&prog[b], __ATOMIC_ACQUIRE, __HIP_MEMORY_SCOPE_AGENT) < ch + 1)
          __builtin_amdgcn_s_sleep(2);
      }
      __syncthreads();   // A
      if (tid < 256){
        const float* src = &fAll[(base + t0)*DD + tid*4];
        float x0 = agLoad_(src+0), x1 = agLoad_(src+1);
        float x2 = agLoad_(src+2), x3 = agLoad_(src+3);
        su.g.sFc[tid*4+0] = x0; su.g.sFc[tid*4+1] = x1;
        su.g.sFc[tid*4+2] = x2; su.g.sFc[tid*4+3] = x3;
      }
      barL_();           // B

      float acc[8];
      #pragma unroll
      for (int uu = 0; uu < 8; uu++) acc[uu] = 0.f;
      for (int k4 = 0; k4 < 32; k4++){
        float4 wv = reinterpret_cast<const float4*>(Wih4)[k4*512 + tid];
        #pragma unroll
        for (int uu = 0; uu < 8; uu++){
          float4 fv = *reinterpret_cast<const float4*>(&su.g.sFc[uu*128 + k4*4]);
          acc[uu] += fv.x*wv.x; acc[uu] += fv.y*wv.y;
          acc[uu] += fv.z*wv.z; acc[uu] += fv.w*wv.w;
        }
      }
      #pragma unroll
      for (int uu = 0; uu < 8; uu++)
        agStore_(&gpre[(base + t0 + uu)*512 + tid], acc[uu] + biasj);
      waitVM_();
      __syncthreads();   // C
      if (tid == 0)
        __hip_atomic_store(&prog[32 + b], ch + 1, __ATOMIC_RELAXED, __HIP_MEMORY_SCOPE_AGENT);
    }

  } else {
    // ==================== LSTM role (direct gp loads, + kOut tail) =========
    const int jo = tid >> 2, kc = tid & 3;
    const int wslot = (jo >> 5)*36 + (jo & 31);

    float whh[4][32];
    #pragma unroll
    for (int g = 0; g < 4; g++){
      const float4* W4 = reinterpret_cast<const float4*>(&Whh[(size_t)(g*128 + jo)*128 + kc*32]);
      #pragma unroll
      for (int i = 0; i < 8; i++){
        float4 v = W4[i];
        whh[g][4*i] = v.x; whh[g][4*i+1] = v.y; whh[g][4*i+2] = v.z; whh[g][4*i+3] = v.w;
      }
    }

    float cin_cur = 0.f;

    for (int ch = 0; ch < TT/8; ch++){
      const int t0 = ch*8;
      if (tid == 0){
        while (__hip_atomic_load(&prog[32 + b], __ATOMIC_ACQUIRE, __HIP_MEMORY_SCOPE_AGENT) < ch + 1)
          __builtin_amdgcn_s_sleep(2);
      }
      __syncthreads();   // A: gpre chunk ready; prev xh/ring/Hh ordered
      if (ch == 0){
        su.l.spv[tid] = __hip_atomic_load(&prevA[base + tid], __ATOMIC_RELAXED, __HIP_MEMORY_SCOPE_AGENT);
        if (tid < DD) su.l.xh[0][(tid >> 5)*36 + (tid & 31)] = 0.f;
      }
      // gp prefetch for step tc=0 (flies across the ch==0 barrier)
      float g0, g1, g2, g3;
      {
        const float* gp = &gpre[(base + t0)*512 + jo];
        g0 = agLoad_(gp);       g1 = agLoad_(gp + 128);
        g2 = agLoad_(gp + 256); g3 = agLoad_(gp + 384);
      }
      if (ch == 0) barL_();     // spv/xh visible

      #pragma unroll
      for (int tc = 0; tc < 8; tc++){
        const int t = t0 + tc, p = t & 1;
        if (tc) barL_();        // xh[p] + ring ready

        int pv2 = -1; float preH = 0.f, preC = 0.f;
        if (t + 1 < TT){
          pv2 = su.l.spv[t + 1];
          if (pv2 >= 0 && pv2 < t){
            if (pv2 >= t0){
              preH = su.l.hRing[(pv2 & 7)*128 + jo];
              preC = su.l.cRing[(pv2 & 7)*128 + jo];
            } else {
              preH = Hh[(base + pv2)*DD + jo];
              preC = Ch[(base + pv2)*DD + jo];
            }
          }
        }
        // next step's gp prefetch (independent; hides under matvec)
        float n0 = 0.f, n1 = 0.f, n2 = 0.f, n3 = 0.f;
        if (tc < 7){
          const float* gp = &gpre[(base + t + 1)*512 + jo];
          n0 = agLoad_(gp);       n1 = agLoad_(gp + 128);
          n2 = agLoad_(gp + 256); n3 = agLoad_(gp + 384);
        }

        float a0=0.f,a1=0.f,a2=0.f,a3=0.f;
        {
          const float4* x4 = reinterpret_cast<const float4*>(&su.l.xh[p][kc*36]);
          #pragma unroll
          for (int i = 0; i < 8; i++){
            float4 xv = x4[i];
            a0 += xv.x*whh[0][4*i]; a0 += xv.y*whh[0][4*i+1]; a0 += xv.z*whh[0][4*i+2]; a0 += xv.w*whh[0][4*i+3];
            a1 += xv.x*whh[1][4*i]; a1 += xv.y*whh[1][4*i+1]; a1 += xv.z*whh[1][4*i+2]; a1 += xv.w*whh[1][4*i+3];
            a2 += xv.x*whh[2][4*i]; a2 += xv.y*whh[2][4*i+1]; a2 += xv.z*whh[2][4*i+2]; a2 += xv.w*whh[2][4*i+3];
            a3 += xv.x*whh[3][4*i]; a3 += xv.y*whh[3][4*i+1]; a3 += xv.z*whh[3][4*i+2]; a3 += xv.w*whh[3][4*i+3];
          }
        }
        a0 = quadSum_(a0); a1 = quadSum_(a1); a2 = quadSum_(a2); a3 = quadSum_(a3);

        const float ig = g0 + a0, fg = g1 + a1, gg = g2 + a2, og = g3 + a3;
        const float cn = fast_sig_(fg)*cin_cur + fast_sig_(ig)*fast_tanh_(gg);
        const float hn = fast_sig_(og)*fast_tanh_(cn);

        if (kc == 0){
          Hh[(base + t)*DD + jo] = hn;
          Ch[(base + t)*DD + jo] = cn;
          su.l.hRing[(t & 7)*128 + jo] = hn;
          su.l.cRing[(t & 7)*128 + jo] = cn;
        }

        float hin_n, cin_n;
        if (pv2 < 0 || pv2 >= t){ hin_n = hn; cin_n = cn; }
        else                     { hin_n = preH; cin_n = preC; }
        if (kc == 0) su.l.xh[1 - p][wslot] = hin_n;
        cin_cur = cin_n;
        g0 = n0; g1 = n1; g2 = n2; g3 = n3;
      }
    }

    // ---- tail: output head for this batch (bit-identical to kOut) ----
    __syncthreads();                       // drains this block's Hh stores
    if (tid < DD) su.l.pw[tid] = p_W[tid];
    barL_();
    {
      const int t = tid;
      const float* hrow = &Hh[(base + t)*DD];
      float s = 0.f;
      #pragma unroll
      for (int k4 = 0; k4 < 32; k4++){
        float4 hv = *reinterpret_cast<const float4*>(&hrow[k4*4]);
        const float* wp = &su.l.pw[k4*4];
        s += hv.x*wp[0] + hv.y*wp[1] + hv.z*wp[2] + hv.w*wp[3];
      }
      out[base + t] = sigmoidf_(s + p_b[0]);
    }
  }
}

// ---------------------------------------------------------------------------
// Launch.
// ---------------------------------------------------------------------------
extern "C" void kernel_launch(void* const* d_in, const int* in_sizes, int n_in,
                              void* d_out, int out_size, void* d_ws, size_t ws_size,
                              hipStream_t stream) {
  const int*   q     = (const int*)  d_in[0];
  const int*   r     = (const int*)  d_in[1];
  const float* k_emb = (const float*)d_in[2];
  const float* Mk    = (const float*)d_in[3];
  const float* Mv0   = (const float*)d_in[4];
  const float* f_W   = (const float*)d_in[5];
  const float* f_b   = (const float*)d_in[6];
  const float* a_W   = (const float*)d_in[7];
  const float* a_b   = (const float*)d_in[8];
  const float* e_W   = (const float*)d_in[9];
  const float* e_b   = (const float*)d_in[10];
  const float* add_W = (const float*)d_in[11];
  const float* add_b = (const float*)d_in[12];
  const float* Wih   = (const float*)d_in[13];
  const float* Whh   = (const float*)d_in[14];
  const float* bih   = (const float*)d_in[15];
  const float* bhh   = (const float*)d_in[16];
  const float* p_W   = (const float*)d_in[17];
  const float* p_b   = (const float*)d_in[18];
  float* out = (float*)d_out;

  char* ws = (char*)d_ws;
  size_t off = 0;
  auto alloc = [&](size_t bytes) -> char* {
    char* p = ws + off;
    off += (bytes + 255) & ~(size_t)255;
    return p;
  };
  float* wAll  = (float*)alloc((size_t)BB*TT*MM*4);
  float* fpre  = (float*)alloc((size_t)BB*TT*DD*4);
  float* ypre  = (float*)alloc((size_t)BB*TT*DD*4);
  float* fAll  = (float*)alloc((size_t)BB*TT*DD*4);
  float* eapre = (float*)alloc((size_t)BB*TT*256*4);
  float* gpre  = (float*)alloc((size_t)BB*TT*512*4);
  float* Hh    = (float*)alloc((size_t)BB*TT*DD*4);
  float* Ch    = (float*)alloc((size_t)BB*TT*DD*4);
  ull*   keyLo = (ull*)  alloc((size_t)BB*TT*8);
  ull*   keyHi = (ull*)  alloc((size_t)BB*TT*8);
  int*   prevA = (int*)  alloc((size_t)BB*TT*4);
  float* Ge    = (float*)alloc((size_t)DD*DD*4);
  float* Ga    = (float*)alloc((size_t)DD*DD*4);
  float* Wih4  = (float*)alloc((size_t)512*DD*4);
  int*   prog  = (int*)  alloc(512);
  (void)ws_size; (void)in_sizes; (void)n_in; (void)out_size;

  kPre  <<<dim3(16, 33), 256, 0, stream>>>(q, r, k_emb, Mk, f_W, f_b, a_W, a_b,
                                           wAll, keyLo, keyHi, fpre, ypre,
                                           e_W, add_W, Ge, Ga, Wih, Wih4, prog);
  kFused<<<128, 512, 0, stream>>>(wAll, fpre, eapre, f_W, Ge, Ga, Mv0, fAll,
                                  Wih4, bih, bhh, keyLo, keyHi, prevA, Whh,
                                  Hh, Ch, gpre, p_W, p_b, out, prog,
                                  ypre, e_W, add_W, e_b, add_b);
}

// Round 13
// 756.170 us; speedup vs baseline: 1.0980x; 1.0980x over previous
//
#include <hip/hip_runtime.h>
#include <cstdint>
#include <cstddef>

// Problem constants
#define NUM_C 4096
#define BB 32
#define TT 512
#define DD 128
#define MM 50

using ull = unsigned long long;

__device__ __forceinline__ float sigmoidf_(float x){ return 1.0f/(1.0f + expf(-x)); }

// Fast transcendentals on the serial critical path: v_exp_f32 / v_rcp_f32
__device__ __forceinline__ float fexp2_(float x){ return __builtin_amdgcn_exp2f(x); }
__device__ __forceinline__ float frcp_(float x){ return __builtin_amdgcn_rcpf(x); }
__device__ __forceinline__ float fast_sig_(float x){
  return frcp_(1.0f + fexp2_(-1.44269504088896341f*x));
}
__device__ __forceinline__ float fast_tanh_(float x){
  float t = fexp2_(2.88539008177792681f*x);     // e^(2x)
  return 1.0f - 2.0f*frcp_(t + 1.0f);
}

// Quad reduction via DPP (VALU pipe, no LDS): sum over lanes {x, x^1, x^2, x^3}
__device__ __forceinline__ float quadSum_(float v){
  int t = __builtin_amdgcn_update_dpp(0, __float_as_int(v), 0xB1, 0xF, 0xF, true);
  v += __int_as_float(t);
  t = __builtin_amdgcn_update_dpp(0, __float_as_int(v), 0x4E, 0xF, 0xF, true);
  v += __int_as_float(t);
  return v;
}

// Relaxed barrier: LDS visibility only (no vmcnt/expcnt drain).
__device__ __forceinline__ void barL_(){
  asm volatile("s_waitcnt lgkmcnt(0)\n\ts_barrier" ::: "memory");
}
// Drain this thread's outstanding vector-memory ops.
__device__ __forceinline__ void waitVM_(){
  asm volatile("s_waitcnt vmcnt(0)" ::: "memory");
}

__device__ __forceinline__ float agLoad_(const float* p){
  return __hip_atomic_load(p, __ATOMIC_RELAXED, __HIP_MEMORY_SCOPE_AGENT);
}
__device__ __forceinline__ void agStore_(float* p, float v){
  __hip_atomic_store(p, v, __ATOMIC_RELAXED, __HIP_MEMORY_SCOPE_AGENT);
}

// ---------------------------------------------------------------------------
// Kernel A (R16-verified): parallel precompute + (by==32) one-time init:
//   - blocks (bx, 0..31): original kPre body (unchanged arithmetic)
//   - blocks (bx, 32):    Ge/Ga weight products, Wih4 repack, flag zeroing.
// ---------------------------------------------------------------------------
__global__ __launch_bounds__(256) void kPre(
    const int* __restrict__ q, const int* __restrict__ r,
    const float* __restrict__ k_emb, const float* __restrict__ Mk,
    const float* __restrict__ f_W, const float* __restrict__ f_b,
    const float* __restrict__ a_W, const float* __restrict__ a_b,
    float* __restrict__ wAll, ull* __restrict__ keyLo, ull* __restrict__ keyHi,
    float* __restrict__ fpre, float* __restrict__ ypre,
    const float* __restrict__ e_W, const float* __restrict__ add_W,
    float* __restrict__ Ge, float* __restrict__ Ga,
    const float* __restrict__ Wih, float* __restrict__ Wih4,
    int* __restrict__ prog)
{
  const int b = blockIdx.y, t0 = blockIdx.x * 32, tid = threadIdx.x;
  __shared__ __align__(16) float sK[32*129];
  __shared__ int sQ[32];
  __shared__ int sR[32];
  __shared__ union UU {
    struct { float sMk[MM*129]; double sZ[32*MM]; } p2;
    float sW2[128*65];
  } u;

  if (b == 32){
    // ---------------- init path ----------------
    const int bx = blockIdx.x;
    if (bx == 0 && tid < 96) prog[tid] = 0;     // pipeline flags
    for (int i = tid; i < 8*128; i += 256){
      int ld = i >> 7, j = i & 127;
      sK[i]        = e_W  [(size_t)(bx*8 + ld)*DD + j];
      sK[1024 + i] = add_W[(size_t)(bx*8 + ld)*DD + j];
    }
    __syncthreads();
    {
      const int ld = tid >> 5, lane = tid & 31;
      const int d = bx*8 + ld;
      float ge[4] = {0.f,0.f,0.f,0.f}, ga[4] = {0.f,0.f,0.f,0.f};
      for (int j = 0; j < 128; j++){
        float sej = sK[ld*128 + j], saj = sK[1024 + ld*128 + j];
        #pragma unroll
        for (int uu = 0; uu < 4; uu++){
          float af = a_W[(size_t)j*(NUM_C + DD) + NUM_C + lane + 32*uu];
          ge[uu] += sej*af;
          ga[uu] += saj*af;
        }
      }
      #pragma unroll
      for (int uu = 0; uu < 4; uu++){
        Ge[(size_t)d*DD + lane + 32*uu] = ge[uu];
        Ga[(size_t)d*DD + lane + 32*uu] = ga[uu];
      }
    }
    for (int i = tid; i < 4096; i += 256){
      int idx = bx*4096 + i;
      int j = idx >> 7, k = idx & 127;
      Wih4[(size_t)(k >> 2)*2048 + j*4 + (k & 3)] = Wih[idx];
    }
    return;
  }

  // ---------------- original kPre body ----------------
  if (tid < 32){ sQ[tid] = q[b*TT + t0 + tid]; sR[tid] = r[b*TT + t0 + tid]; }
  __syncthreads();
  for (int i = tid; i < 32*128; i += 256){
    int tl = i >> 7, j = i & 127;
    sK[tl*129 + j] = k_emb[(size_t)sQ[tl]*DD + j];
  }
  for (int i = tid; i < MM*128; i += 256){
    int m = i >> 7, j = i & 127;
    u.p2.sMk[m*129 + j] = Mk[i];
  }
  __syncthreads();

  for (int idx = tid; idx < 32*MM; idx += 256){
    int tl = idx / MM, m = idx - tl*MM;
    double z = 0.0;
    for (int j = 0; j < DD; j++)
      z += (double)sK[tl*129 + j] * (double)u.p2.sMk[m*129 + j];
    u.p2.sZ[tl*MM + m] = z;
  }
  __syncthreads();

  {
    int tl = tid >> 3, l8 = tid & 7;
    double zmax = -1e300;
    for (int m = l8; m < MM; m += 8) zmax = fmax(zmax, u.p2.sZ[tl*MM + m]);
    for (int s = 1; s < 8; s <<= 1) zmax = fmax(zmax, __shfl_xor(zmax, s));
    double se = 0.0;
    for (int m = l8; m < MM; m += 8){
      double e = exp(u.p2.sZ[tl*MM + m] - zmax);
      u.p2.sZ[tl*MM + m] = e;
      se += e;
    }
    for (int s = 1; s < 8; s <<= 1) se += __shfl_xor(se, s);
    double inv = 1.0 / se;
    ull klo = 0, khi = 0;
    for (int m = l8; m < MM; m += 8){
      double w = u.p2.sZ[tl*MM + m] * inv;
      wAll[((size_t)(b*TT + t0 + tl))*MM + m] = (float)w;
      double tw = fmin((w - 0.075)/(0.088 - 0.075), (1.0 - w)/(1.0 - 0.088));
      tw = fmax(tw, 0.0);
      ull iv = (tw >= 0.6) ? 2ull : ((tw >= 0.1) ? 1ull : 0ull);
      if (m < 32) klo |= iv << (2*m); else khi |= iv << (2*(m-32));
    }
    for (int s = 1; s < 8; s <<= 1){ klo |= __shfl_xor(klo, s); khi |= __shfl_xor(khi, s); }
    if (l8 == 0){ keyLo[b*TT + t0 + tl] = klo; keyHi[b*TT + t0 + tl] = khi; }
  }

  {
    const int dq = tid & 31, tq = tid >> 5;
    float acc[4][4];
    #pragma unroll
    for (int a = 0; a < 4; a++){ acc[a][0]=0.f; acc[a][1]=0.f; acc[a][2]=0.f; acc[a][3]=0.f; }
    for (int jh = 0; jh < 2; jh++){
      __syncthreads();
      for (int i = tid; i < 128*64; i += 256){
        int dd = i >> 6, jj = i & 63;
        u.sW2[dd*65 + jj] = f_W[dd*256 + 128 + jh*64 + jj];
      }
      __syncthreads();
      for (int jj = 0; jj < 64; jj++){
        float kv[4], wv[4];
        #pragma unroll
        for (int a = 0; a < 4; a++) kv[a] = sK[(tq*4 + a)*129 + jh*64 + jj];
        #pragma unroll
        for (int c = 0; c < 4; c++) wv[c] = u.sW2[(dq*4 + c)*65 + jj];
        #pragma unroll
        for (int a = 0; a < 4; a++){
          acc[a][0] += kv[a]*wv[0]; acc[a][1] += kv[a]*wv[1];
          acc[a][2] += kv[a]*wv[2]; acc[a][3] += kv[a]*wv[3];
        }
      }
    }
    #pragma unroll
    for (int a = 0; a < 4; a++){
      int tl = tq*4 + a;
      #pragma unroll
      for (int c = 0; c < 4; c++){
        int d = dq*4 + c;
        fpre[((size_t)(b*TT + t0 + tl))*DD + d] = acc[a][c] + f_b[d];
      }
    }
  }

  for (int i = tid; i < 32*DD; i += 256){
    int tl = i >> 7, d = i & 127;
    ypre[((size_t)(b*TT + t0 + tl))*DD + d] =
        a_W[(size_t)d*(NUM_C + DD) + sQ[tl]] * (float)sR[tl] + a_b[d];
  }
}

// ---------------------------------------------------------------------------
// Kernel EA: eapre GEMM (R15 version, separate node — R16's in-kernel role
// regressed).
// ---------------------------------------------------------------------------
__global__ __launch_bounds__(256) void kEA(
    const float* __restrict__ ypre, const float* __restrict__ e_W,
    const float* __restrict__ add_W, const float* __restrict__ e_b,
    const float* __restrict__ add_b, float* __restrict__ eapre)
{
  const int jt = blockIdx.x;   // 0..3  (64 output cols each)
  const int rt = blockIdx.y;   // 0..511 (32 rows each)
  const int tid = threadIdx.x;
  __shared__ float sW[64*129];
  __shared__ float sF[32*129];
  for (int i = tid; i < 64*128; i += 256){
    int jj = i >> 7, k = i & 127;
    int j = jt*64 + jj;
    sW[jj*129 + k] = (j < 128) ? e_W[(size_t)j*DD + k] : add_W[(size_t)(j-128)*DD + k];
  }
  for (int i = tid; i < 32*128; i += 256){
    int rr = i >> 7, k = i & 127;
    sF[rr*129 + k] = ypre[(size_t)(rt*32 + rr)*DD + k];
  }
  __syncthreads();
  const int jq = tid & 31, rq = tid >> 5;
  float acc[4][2];
  #pragma unroll
  for (int a = 0; a < 4; a++){ acc[a][0] = 0.f; acc[a][1] = 0.f; }
  for (int k = 0; k < 128; k++){
    float fv[4], wv[2];
    #pragma unroll
    for (int a = 0; a < 4; a++) fv[a] = sF[(rq*4 + a)*129 + k];
    wv[0] = sW[(jq*2 + 0)*129 + k];
    wv[1] = sW[(jq*2 + 1)*129 + k];
    #pragma unroll
    for (int a = 0; a < 4; a++){ acc[a][0] += fv[a]*wv[0]; acc[a][1] += fv[a]*wv[1]; }
  }
  #pragma unroll
  for (int a = 0; a < 4; a++){
    int rowi = rt*32 + rq*4 + a;
    #pragma unroll
    for (int c = 0; c < 2; c++){
      int j = jt*64 + jq*2 + c;
      float bj = (j < 128) ? e_b[j] : add_b[j - 128];
      eapre[(size_t)rowi*256 + j] = acc[a][c] + bj;
    }
  }
}

// ---------------------------------------------------------------------------
// Kernel F (R17): 3-role fused pipeline.
//   Blocks  0..31: memory recurrence (R15 verbatim) -> fAll, prog[b]
//   Blocks 32..63: gates GEMM — NO prephase (starts chunk 0 immediately;
//                  R15's kMatch prephase here delayed the whole pipeline).
//   Blocks 64..95: LSTM — PREPHASE = key-match scan writing spv directly in
//                  LDS (absorbed into the role's startup idle; prevA buffer
//                  and its drain/flag coupling eliminated); gbuf staging
//                  (R15); TAIL = kOut for this batch.
// ---------------------------------------------------------------------------
__global__ __launch_bounds__(512, 2) __attribute__((amdgpu_waves_per_eu(2, 2)))
void kFused(
    const float* __restrict__ wAll, const float* __restrict__ fpre,
    const float* __restrict__ eapre, const float* __restrict__ f_W,
    const float* __restrict__ Ge, const float* __restrict__ Ga,
    const float* __restrict__ Mv0, float* __restrict__ fAll,
    const float* __restrict__ Wih4, const float* __restrict__ bih,
    const float* __restrict__ bhh, const ull* __restrict__ keyLo,
    const ull* __restrict__ keyHi,
    const float* __restrict__ Whh, float* __restrict__ Hh,
    float* __restrict__ Ch, float* __restrict__ gpre,
    const float* __restrict__ p_W, const float* __restrict__ p_b,
    float* __restrict__ out, int* __restrict__ prog)
{
  const int tid = threadIdx.x;
  const int b = blockIdx.x & 31;
  const size_t base = (size_t)b*TT;

  __shared__ __align__(16) union SU {
    struct {
      float bufR[144]; float bufF[144]; float sW9[9*52];
      float sF8[8*128]; float sEA8[8*256]; float fO8[8*128];
    } m;
    struct { float sFc[8*128]; } g;
    struct {
      float xh[2][144]; float gbuf[8*512]; int spv[TT];
      float hRing[8*128]; float cRing[8*128]; float pw[DD];
    } l;
  } su;

  if (blockIdx.x < 32){
    // ==================== memory-recurrence role (R15 verbatim) ============
    const int dd = tid >> 2, kc = tid & 3, m0 = kc*13;
    const int wslot = (dd >> 5)*36 + (dd & 31);

    float mv[13];
    #pragma unroll
    for (int i = 0; i < 13; i++){
      int m = m0 + i;
      mv[i] = (m < MM) ? Mv0[(size_t)m*DD + dd] : 0.f;
    }
    float wf[32], ge[32], ga[32];
    {
      const float4* p;
      p = reinterpret_cast<const float4*>(&f_W[dd*256 + kc*32]);
      #pragma unroll
      for (int i = 0; i < 8; i++){ float4 v = p[i]; wf[4*i]=v.x; wf[4*i+1]=v.y; wf[4*i+2]=v.z; wf[4*i+3]=v.w; }
      p = reinterpret_cast<const float4*>(&Ge[(size_t)dd*DD + kc*32]);
      #pragma unroll
      for (int i = 0; i < 8; i++){ float4 v = p[i]; ge[4*i]=v.x; ge[4*i+1]=v.y; ge[4*i+2]=v.z; ge[4*i+3]=v.w; }
      p = reinterpret_cast<const float4*>(&Ga[(size_t)dd*DD + kc*32]);
      #pragma unroll
      for (int i = 0; i < 8; i++){ float4 v = p[i]; ga[4*i]=v.x; ga[4*i+1]=v.y; ga[4*i+2]=v.z; ga[4*i+3]=v.w; }
    }

    const int rr0 = tid / 50, mm0 = tid - rr0*50;   // valid when tid < 450
    if (tid < 18){ int rr = tid >> 1; su.m.sW9[rr*52 + 50 + (tid & 1)] = 0.f; }

    float4 pF = {0.f,0.f,0.f,0.f}, pEA = {0.f,0.f,0.f,0.f};
    float pW = 0.f;
    if (tid < 256) pF = reinterpret_cast<const float4*>(&fpre[base*DD])[tid];
    pEA = reinterpret_cast<const float4*>(&eapre[base*256])[tid];
    if (tid < 450) pW = wAll[(base + rr0)*MM + mm0];

    float wreg[13];

    for (int ch = 0; ch < TT/8; ch++){
      const int t0 = ch*8;
      if (ch){
        if (tid < 256){
          float4 v = reinterpret_cast<const float4*>(su.m.fO8)[tid];
          float* dst = &fAll[(base + t0 - 8)*DD + tid*4];
          agStore_(dst+0, v.x); agStore_(dst+1, v.y);
          agStore_(dst+2, v.z); agStore_(dst+3, v.w);
        }
      }
      if (tid < 256) reinterpret_cast<float4*>(su.m.sF8)[tid] = pF;
      reinterpret_cast<float4*>(su.m.sEA8)[tid] = pEA;
      if (tid < 450) su.m.sW9[rr0*52 + mm0] = pW;
      if (ch && tid < 256) waitVM_();     // chunk stores complete before flag
      if (t0 + 8 < TT){
        if (tid < 256) pF = reinterpret_cast<const float4*>(&fpre[(base + t0 + 8)*DD])[tid];
        pEA = reinterpret_cast<const float4*>(&eapre[(base + t0 + 8)*256])[tid];
        if (tid < 450) pW = (t0 + 8 + rr0 < TT) ? wAll[(base + t0 + 8 + rr0)*MM + mm0] : 0.f;
      }
      barL_();   // R: chunk published (and all fAll stores drained)
      if (ch && tid == 0)
        __hip_atomic_store(&prog[b], ch, __ATOMIC_RELAXED, __HIP_MEMORY_SCOPE_AGENT);

      if (ch == 0){
        #pragma unroll
        for (int i = 0; i < 13; i++) wreg[i] = su.m.sW9[m0 + i];
        float r = 0.f;
        #pragma unroll
        for (int i = 0; i < 13; i++) r += wreg[i]*mv[i];
        r = quadSum_(r);
        if (kc == 0) su.m.bufR[wslot] = r;
        barL_();
      }

      #pragma unroll
      for (int tc = 0; tc < 8; tc++){
        float wn[13];
        #pragma unroll
        for (int i = 0; i < 13; i++) wn[i] = su.m.sW9[(tc+1)*52 + m0 + i];

        // ---- stage F: f = tanh(read @ f_Wr.T + fpre) ----
        {
          const float4* x4 = reinterpret_cast<const float4*>(&su.m.bufR[kc*36]);
          float a0=0.f,a1=0.f,a2=0.f,a3=0.f;
          #pragma unroll
          for (int i = 0; i < 8; i++){
            float4 xv = x4[i];
            a0 += xv.x*wf[4*i]; a1 += xv.y*wf[4*i+1]; a2 += xv.z*wf[4*i+2]; a3 += xv.w*wf[4*i+3];
          }
          float s = quadSum_((a0+a1)+(a2+a3));
          float fval = fast_tanh_(s + su.m.sF8[tc*128 + dd]);
          if (kc == 0){
            su.m.bufF[wslot] = fval;
            su.m.fO8[tc*128 + dd] = fval;
          }
        }
        barL_();   // B

        // ---- stage EA: e,a from f; mv update; read_{t+1} = wn . mv_new ----
        {
          const float4* x4 = reinterpret_cast<const float4*>(&su.m.bufF[kc*36]);
          float e0=0.f,e1=0.f,g0=0.f,g1=0.f;
          #pragma unroll
          for (int i = 0; i < 8; i++){
            float4 xv = x4[i];
            e0 += xv.x*ge[4*i];   e1 += xv.y*ge[4*i+1];
            e0 += xv.z*ge[4*i+2]; e1 += xv.w*ge[4*i+3];
            g0 += xv.x*ga[4*i];   g1 += xv.y*ga[4*i+1];
            g0 += xv.z*ga[4*i+2]; g1 += xv.w*ga[4*i+3];
          }
          float ep = quadSum_(e0 + e1);
          float ap = quadSum_(g0 + g1);
          float e_d = fast_sig_(ep + su.m.sEA8[tc*256 + dd]);
          float a_d = fast_tanh_(ap + su.m.sEA8[tc*256 + 128 + dd]);
          float rp0 = 0.f, rp1 = 0.f;
          #pragma unroll
          for (int i = 0; i < 13; i++){
            float t = __builtin_fmaf(-e_d, mv[i], a_d);
            mv[i] = __builtin_fmaf(wreg[i], t, mv[i]);
            if (i & 1) rp1 = __builtin_fmaf(wn[i], mv[i], rp1);
            else       rp0 = __builtin_fmaf(wn[i], mv[i], rp0);
          }
          float rd = quadSum_(rp0 + rp1);
          if (kc == 0) su.m.bufR[wslot] = rd;
        }
        #pragma unroll
        for (int i = 0; i < 13; i++) wreg[i] = wn[i];
        barL_();   // C
      }
    }

    // tail: store last chunk + final flag
    if (tid < 256){
      float4 v = reinterpret_cast<const float4*>(su.m.fO8)[tid];
      float* dst = &fAll[(base + TT - 8)*DD + tid*4];
      agStore_(dst+0, v.x); agStore_(dst+1, v.y);
      agStore_(dst+2, v.z); agStore_(dst+3, v.w);
      waitVM_();
    }
    __syncthreads();
    if (tid == 0)
      __hip_atomic_store(&prog[b], TT/8, __ATOMIC_RELAXED, __HIP_MEMORY_SCOPE_AGENT);

  } else if (blockIdx.x < 64){
    // ==================== gates-GEMM role (no prephase) ====================
    const float biasj = bih[tid] + bhh[tid];   // thread owns gate-column j = tid

    for (int ch = 0; ch < TT/8; ch++){
      const int t0 = ch*8;
      if (tid == 0){
        while (__hip_atomic_load(&prog[b], __ATOMIC_ACQUIRE, __HIP_MEMORY_SCOPE_AGENT) < ch + 1)
          __builtin_amdgcn_s_sleep(2);
      }
      __syncthreads();   // A: join spin; prev chunk's sFc reads/stores done
      if (tid < 256){
        const float* src = &fAll[(base + t0)*DD + tid*4];
        float x0 = agLoad_(src+0), x1 = agLoad_(src+1);
        float x2 = agLoad_(src+2), x3 = agLoad_(src+3);
        su.g.sFc[tid*4+0] = x0; su.g.sFc[tid*4+1] = x1;
        su.g.sFc[tid*4+2] = x2; su.g.sFc[tid*4+3] = x3;
      }
      barL_();           // B: sFc published

      float acc[8];
      #pragma unroll
      for (int uu = 0; uu < 8; uu++) acc[uu] = 0.f;
      for (int k4 = 0; k4 < 32; k4++){
        float4 wv = reinterpret_cast<const float4*>(Wih4)[k4*512 + tid];
        #pragma unroll
        for (int uu = 0; uu < 8; uu++){
          float4 fv = *reinterpret_cast<const float4*>(&su.g.sFc[uu*128 + k4*4]);
          acc[uu] += fv.x*wv.x; acc[uu] += fv.y*wv.y;
          acc[uu] += fv.z*wv.z; acc[uu] += fv.w*wv.w;
        }
      }
      #pragma unroll
      for (int uu = 0; uu < 8; uu++)
        agStore_(&gpre[(base + t0 + uu)*512 + tid], acc[uu] + biasj);
      waitVM_();
      __syncthreads();   // C: all threads' gpre stores drained
      if (tid == 0)
        __hip_atomic_store(&prog[32 + b], ch + 1, __ATOMIC_RELAXED, __HIP_MEMORY_SCOPE_AGENT);
    }

  } else {
    // ==================== LSTM role (scan prephase + kOut tail) ============
    const int jo = tid >> 2, kc = tid & 3;
    const int wslot = (jo >> 5)*36 + (jo & 31);

    float whh[4][32];
    #pragma unroll
    for (int g = 0; g < 4; g++){
      const float4* W4 = reinterpret_cast<const float4*>(&Whh[(size_t)(g*128 + jo)*128 + kc*32]);
      #pragma unroll
      for (int i = 0; i < 8; i++){
        float4 v = W4[i];
        whh[g][4*i] = v.x; whh[g][4*i+1] = v.y; whh[g][4*i+2] = v.z; whh[g][4*i+3] = v.w;
      }
    }

    // --- prephase: key-match scan -> spv (LDS), absorbed into startup idle.
    //     slo/shi overlay gbuf (scan completes before gbuf first used).
    {
      ull* slo = reinterpret_cast<ull*>(su.l.gbuf);   // 512 ulls (4 KB)
      ull* shi = slo + TT;                            // next 512 ulls
      slo[tid] = keyLo[base + tid];
      shi[tid] = keyHi[base + tid];
      barL_();
      const ull mylo = slo[tid], myhi = shi[tid];
      int found = -1;
      for (int j = tid - 1; j >= 0; j--){
        if (slo[j] == mylo && shi[j] == myhi){ found = j; break; }
      }
      su.l.spv[tid] = found;
      if (tid < DD) su.l.xh[0][(tid >> 5)*36 + (tid & 31)] = 0.f;
      // visibility of spv/xh: first __syncthreads (A) below
    }

    float cin_cur = 0.f;

    for (int ch = 0; ch < TT/8; ch++){
      const int t0 = ch*8;
      if (tid == 0){
        while (__hip_atomic_load(&prog[32 + b], __ATOMIC_ACQUIRE, __HIP_MEMORY_SCOPE_AGENT) < ch + 1)
          __builtin_amdgcn_s_sleep(2);
      }
      __syncthreads();   // A: join spin; prev gbuf reads + Hh/Ch stores done
      // stage gpre chunk (16 KB): thread -> 8 contiguous floats
      {
        const float* src = &gpre[(base + t0)*512 + tid*8];
        float x0 = agLoad_(src+0), x1 = agLoad_(src+1);
        float x2 = agLoad_(src+2), x3 = agLoad_(src+3);
        float x4 = agLoad_(src+4), x5 = agLoad_(src+5);
        float x6 = agLoad_(src+6), x7 = agLoad_(src+7);
        float* d = &su.l.gbuf[tid*8];
        d[0]=x0; d[1]=x1; d[2]=x2; d[3]=x3; d[4]=x4; d[5]=x5; d[6]=x6; d[7]=x7;
      }
      barL_();           // B: gbuf ready (+ ch==0: spv/xh visible)

      #pragma unroll
      for (int tc = 0; tc < 8; tc++){
        const int t = t0 + tc, p = t & 1;
        if (tc) barL_();                 // xh[p] + ring ready

        int pv2 = -1; float preH = 0.f, preC = 0.f;
        if (t + 1 < TT){
          pv2 = su.l.spv[t + 1];
          if (pv2 >= 0 && pv2 < t){
            if (pv2 >= t0){              // in-chunk: LDS ring
              preH = su.l.hRing[(pv2 & 7)*128 + jo];
              preC = su.l.cRing[(pv2 & 7)*128 + jo];
            } else {                     // older chunk: global (same block wrote it)
              preH = Hh[(base + pv2)*DD + jo];
              preC = Ch[(base + pv2)*DD + jo];
            }
          }
        }

        float gp0 = su.l.gbuf[tc*512 + jo];
        float gp1 = su.l.gbuf[tc*512 + 128 + jo];
        float gp2 = su.l.gbuf[tc*512 + 256 + jo];
        float gp3 = su.l.gbuf[tc*512 + 384 + jo];

        float a0=0.f,a1=0.f,a2=0.f,a3=0.f;
        {
          const float4* x4 = reinterpret_cast<const float4*>(&su.l.xh[p][kc*36]);
          #pragma unroll
          for (int i = 0; i < 8; i++){
            float4 xv = x4[i];
            a0 += xv.x*whh[0][4*i]; a0 += xv.y*whh[0][4*i+1]; a0 += xv.z*whh[0][4*i+2]; a0 += xv.w*whh[0][4*i+3];
            a1 += xv.x*whh[1][4*i]; a1 += xv.y*whh[1][4*i+1]; a1 += xv.z*whh[1][4*i+2]; a1 += xv.w*whh[1][4*i+3];
            a2 += xv.x*whh[2][4*i]; a2 += xv.y*whh[2][4*i+1]; a2 += xv.z*whh[2][4*i+2]; a2 += xv.w*whh[2][4*i+3];
            a3 += xv.x*whh[3][4*i]; a3 += xv.y*whh[3][4*i+1]; a3 += xv.z*whh[3][4*i+2]; a3 += xv.w*whh[3][4*i+3];
          }
        }
        a0 = quadSum_(a0); a1 = quadSum_(a1); a2 = quadSum_(a2); a3 = quadSum_(a3);

        const float ig = gp0 + a0, fg = gp1 + a1, gg = gp2 + a2, og = gp3 + a3;
        const float cn = fast_sig_(fg)*cin_cur + fast_sig_(ig)*fast_tanh_(gg);
        const float hn = fast_sig_(og)*fast_tanh_(cn);

        if (kc == 0){
          Hh[(base + t)*DD + jo] = hn;
          Ch[(base + t)*DD + jo] = cn;
          su.l.hRing[(t & 7)*128 + jo] = hn;
          su.l.cRing[(t & 7)*128 + jo] = cn;
        }

        float hin_n, cin_n;
        if (pv2 < 0 || pv2 >= t){ hin_n = hn; cin_n = cn; }       // carry
        else                     { hin_n = preH; cin_n = preC; }   // skip
        if (kc == 0) su.l.xh[1 - p][wslot] = hin_n;
        cin_cur = cin_n;
      }
    }

    // ---- tail: output head for this batch (bit-identical to kOut) ----
    __syncthreads();                       // drains this block's Hh stores
    if (tid < DD) su.l.pw[tid] = p_W[tid];
    barL_();
    {
      const int t = tid;
      const float* hrow = &Hh[(base + t)*DD];
      float s = 0.f;
      #pragma unroll
      for (int k4 = 0; k4 < 32; k4++){
        float4 hv = *reinterpret_cast<const float4*>(&hrow[k4*4]);
        const float* wp = &su.l.pw[k4*4];
        s += hv.x*wp[0] + hv.y*wp[1] + hv.z*wp[2] + hv.w*wp[3];
      }
      out[base + t] = sigmoidf_(s + p_b[0]);
    }
  }
}

// ---------------------------------------------------------------------------
// Launch.
// ---------------------------------------------------------------------------
extern "C" void kernel_launch(void* const* d_in, const int* in_sizes, int n_in,
                              void* d_out, int out_size, void* d_ws, size_t ws_size,
                              hipStream_t stream) {
  const int*   q     = (const int*)  d_in[0];
  const int*   r     = (const int*)  d_in[1];
  const float* k_emb = (const float*)d_in[2];
  const float* Mk    = (const float*)d_in[3];
  const float* Mv0   = (const float*)d_in[4];
  const float* f_W   = (const float*)d_in[5];
  const float* f_b   = (const float*)d_in[6];
  const float* a_W   = (const float*)d_in[7];
  const float* a_b   = (const float*)d_in[8];
  const float* e_W   = (const float*)d_in[9];
  const float* e_b   = (const float*)d_in[10];
  const float* add_W = (const float*)d_in[11];
  const float* add_b = (const float*)d_in[12];
  const float* Wih   = (const float*)d_in[13];
  const float* Whh   = (const float*)d_in[14];
  const float* bih   = (const float*)d_in[15];
  const float* bhh   = (const float*)d_in[16];
  const float* p_W   = (const float*)d_in[17];
  const float* p_b   = (const float*)d_in[18];
  float* out = (float*)d_out;

  char* ws = (char*)d_ws;
  size_t off = 0;
  auto alloc = [&](size_t bytes) -> char* {
    char* p = ws + off;
    off += (bytes + 255) & ~(size_t)255;
    return p;
  };
  float* wAll  = (float*)alloc((size_t)BB*TT*MM*4);
  float* fpre  = (float*)alloc((size_t)BB*TT*DD*4);
  float* ypre  = (float*)alloc((size_t)BB*TT*DD*4);
  float* fAll  = (float*)alloc((size_t)BB*TT*DD*4);
  float* eapre = (float*)alloc((size_t)BB*TT*256*4);
  float* gpre  = (float*)alloc((size_t)BB*TT*512*4);
  float* Hh    = (float*)alloc((size_t)BB*TT*DD*4);
  float* Ch    = (float*)alloc((size_t)BB*TT*DD*4);
  ull*   keyLo = (ull*)  alloc((size_t)BB*TT*8);
  ull*   keyHi = (ull*)  alloc((size_t)BB*TT*8);
  float* Ge    = (float*)alloc((size_t)DD*DD*4);
  float* Ga    = (float*)alloc((size_t)DD*DD*4);
  float* Wih4  = (float*)alloc((size_t)512*DD*4);
  int*   prog  = (int*)  alloc(512);
  (void)ws_size; (void)in_sizes; (void)n_in; (void)out_size;

  kPre  <<<dim3(16, 33), 256, 0, stream>>>(q, r, k_emb, Mk, f_W, f_b, a_W, a_b,
                                           wAll, keyLo, keyHi, fpre, ypre,
                                           e_W, add_W, Ge, Ga, Wih, Wih4, prog);
  kEA   <<<dim3(4, 512), 256, 0, stream>>>(ypre, e_W, add_W, e_b, add_b, eapre);
  kFused<<<96, 512, 0, stream>>>(wAll, fpre, eapre, f_W, Ge, Ga, Mv0, fAll,
                                 Wih4, bih, bhh, keyLo, keyHi, Whh,
                                 Hh, Ch, gpre, p_W, p_b, out, prog);
}

// Round 14
// 743.694 us; speedup vs baseline: 1.1164x; 1.0168x over previous
//
#include <hip/hip_runtime.h>
#include <cstdint>
#include <cstddef>

// Problem constants
#define NUM_C 4096
#define BB 32
#define TT 512
#define DD 128
#define MM 50

using ull = unsigned long long;

__device__ __forceinline__ float sigmoidf_(float x){ return 1.0f/(1.0f + expf(-x)); }

// Fast transcendentals on the serial critical path: v_exp_f32 / v_rcp_f32
__device__ __forceinline__ float fexp2_(float x){ return __builtin_amdgcn_exp2f(x); }
__device__ __forceinline__ float frcp_(float x){ return __builtin_amdgcn_rcpf(x); }
__device__ __forceinline__ float fast_sig_(float x){
  return frcp_(1.0f + fexp2_(-1.44269504088896341f*x));
}
__device__ __forceinline__ float fast_tanh_(float x){
  float t = fexp2_(2.88539008177792681f*x);     // e^(2x)
  return 1.0f - 2.0f*frcp_(t + 1.0f);
}

// Quad reduction via DPP (VALU pipe, no LDS): sum over lanes {x, x^1, x^2, x^3}
__device__ __forceinline__ float quadSum_(float v){
  int t = __builtin_amdgcn_update_dpp(0, __float_as_int(v), 0xB1, 0xF, 0xF, true);
  v += __int_as_float(t);
  t = __builtin_amdgcn_update_dpp(0, __float_as_int(v), 0x4E, 0xF, 0xF, true);
  v += __int_as_float(t);
  return v;
}

// Relaxed barrier: LDS visibility only (no vmcnt/expcnt drain).
__device__ __forceinline__ void barL_(){
  asm volatile("s_waitcnt lgkmcnt(0)\n\ts_barrier" ::: "memory");
}
// Drain this thread's outstanding vector-memory ops.
__device__ __forceinline__ void waitVM_(){
  asm volatile("s_waitcnt vmcnt(0)" ::: "memory");
}

__device__ __forceinline__ float agLoad_(const float* p){
  return __hip_atomic_load(p, __ATOMIC_RELAXED, __HIP_MEMORY_SCOPE_AGENT);
}
__device__ __forceinline__ void agStore_(float* p, float v){
  __hip_atomic_store(p, v, __ATOMIC_RELAXED, __HIP_MEMORY_SCOPE_AGENT);
}

// ---------------------------------------------------------------------------
// Kernel A (R18): parallel precompute + eapre fold + (by==32) init.
//   - blocks (bx, 0..31): original kPre body, then ypre -> LDS and the
//     kEA GEMM for these 32 rows (kEA-identical k-ascending accumulation,
//     identical output layout). ypre global buffer eliminated.
//   - blocks (bx, 32): Ge/Ga weight products, Wih4 repack, flag zeroing.
// ---------------------------------------------------------------------------
__global__ __launch_bounds__(256) void kPre(
    const int* __restrict__ q, const int* __restrict__ r,
    const float* __restrict__ k_emb, const float* __restrict__ Mk,
    const float* __restrict__ f_W, const float* __restrict__ f_b,
    const float* __restrict__ a_W, const float* __restrict__ a_b,
    float* __restrict__ wAll, ull* __restrict__ keyLo, ull* __restrict__ keyHi,
    float* __restrict__ fpre,
    const float* __restrict__ e_W, const float* __restrict__ add_W,
    const float* __restrict__ e_b, const float* __restrict__ add_b,
    float* __restrict__ eapre,
    float* __restrict__ Ge, float* __restrict__ Ga,
    const float* __restrict__ Wih, float* __restrict__ Wih4,
    int* __restrict__ prog)
{
  const int b = blockIdx.y, t0 = blockIdx.x * 32, tid = threadIdx.x;
  __shared__ __align__(16) float sK[32*129];
  __shared__ int sQ[32];
  __shared__ int sR[32];
  __shared__ union UU {
    struct { float sMk[MM*129]; double sZ[32*MM]; } p2;
    float sW2[128*65];     // also reused (64*129 <= 128*65) for eapre tiles
  } u;

  if (b == 32){
    // ---------------- init path ----------------
    const int bx = blockIdx.x;
    if (bx == 0 && tid < 96) prog[tid] = 0;     // pipeline flags
    for (int i = tid; i < 8*128; i += 256){
      int ld = i >> 7, j = i & 127;
      sK[i]        = e_W  [(size_t)(bx*8 + ld)*DD + j];
      sK[1024 + i] = add_W[(size_t)(bx*8 + ld)*DD + j];
    }
    __syncthreads();
    {
      const int ld = tid >> 5, lane = tid & 31;
      const int d = bx*8 + ld;
      float ge[4] = {0.f,0.f,0.f,0.f}, ga[4] = {0.f,0.f,0.f,0.f};
      for (int j = 0; j < 128; j++){
        float sej = sK[ld*128 + j], saj = sK[1024 + ld*128 + j];
        #pragma unroll
        for (int uu = 0; uu < 4; uu++){
          float af = a_W[(size_t)j*(NUM_C + DD) + NUM_C + lane + 32*uu];
          ge[uu] += sej*af;
          ga[uu] += saj*af;
        }
      }
      #pragma unroll
      for (int uu = 0; uu < 4; uu++){
        Ge[(size_t)d*DD + lane + 32*uu] = ge[uu];
        Ga[(size_t)d*DD + lane + 32*uu] = ga[uu];
      }
    }
    for (int i = tid; i < 4096; i += 256){
      int idx = bx*4096 + i;
      int j = idx >> 7, k = idx & 127;
      Wih4[(size_t)(k >> 2)*2048 + j*4 + (k & 3)] = Wih[idx];
    }
    return;
  }

  // ---------------- original kPre body ----------------
  if (tid < 32){ sQ[tid] = q[b*TT + t0 + tid]; sR[tid] = r[b*TT + t0 + tid]; }
  __syncthreads();
  for (int i = tid; i < 32*128; i += 256){
    int tl = i >> 7, j = i & 127;
    sK[tl*129 + j] = k_emb[(size_t)sQ[tl]*DD + j];
  }
  for (int i = tid; i < MM*128; i += 256){
    int m = i >> 7, j = i & 127;
    u.p2.sMk[m*129 + j] = Mk[i];
  }
  __syncthreads();

  for (int idx = tid; idx < 32*MM; idx += 256){
    int tl = idx / MM, m = idx - tl*MM;
    double z = 0.0;
    for (int j = 0; j < DD; j++)
      z += (double)sK[tl*129 + j] * (double)u.p2.sMk[m*129 + j];
    u.p2.sZ[tl*MM + m] = z;
  }
  __syncthreads();

  {
    int tl = tid >> 3, l8 = tid & 7;
    double zmax = -1e300;
    for (int m = l8; m < MM; m += 8) zmax = fmax(zmax, u.p2.sZ[tl*MM + m]);
    for (int s = 1; s < 8; s <<= 1) zmax = fmax(zmax, __shfl_xor(zmax, s));
    double se = 0.0;
    for (int m = l8; m < MM; m += 8){
      double e = exp(u.p2.sZ[tl*MM + m] - zmax);
      u.p2.sZ[tl*MM + m] = e;
      se += e;
    }
    for (int s = 1; s < 8; s <<= 1) se += __shfl_xor(se, s);
    double inv = 1.0 / se;
    ull klo = 0, khi = 0;
    for (int m = l8; m < MM; m += 8){
      double w = u.p2.sZ[tl*MM + m] * inv;
      wAll[((size_t)(b*TT + t0 + tl))*MM + m] = (float)w;
      double tw = fmin((w - 0.075)/(0.088 - 0.075), (1.0 - w)/(1.0 - 0.088));
      tw = fmax(tw, 0.0);
      ull iv = (tw >= 0.6) ? 2ull : ((tw >= 0.1) ? 1ull : 0ull);
      if (m < 32) klo |= iv << (2*m); else khi |= iv << (2*(m-32));
    }
    for (int s = 1; s < 8; s <<= 1){ klo |= __shfl_xor(klo, s); khi |= __shfl_xor(khi, s); }
    if (l8 == 0){ keyLo[b*TT + t0 + tl] = klo; keyHi[b*TT + t0 + tl] = khi; }
  }

  {
    const int dq = tid & 31, tq = tid >> 5;
    float acc[4][4];
    #pragma unroll
    for (int a = 0; a < 4; a++){ acc[a][0]=0.f; acc[a][1]=0.f; acc[a][2]=0.f; acc[a][3]=0.f; }
    for (int jh = 0; jh < 2; jh++){
      __syncthreads();
      for (int i = tid; i < 128*64; i += 256){
        int dd = i >> 6, jj = i & 63;
        u.sW2[dd*65 + jj] = f_W[dd*256 + 128 + jh*64 + jj];
      }
      __syncthreads();
      for (int jj = 0; jj < 64; jj++){
        float kv[4], wv[4];
        #pragma unroll
        for (int a = 0; a < 4; a++) kv[a] = sK[(tq*4 + a)*129 + jh*64 + jj];
        #pragma unroll
        for (int c = 0; c < 4; c++) wv[c] = u.sW2[(dq*4 + c)*65 + jj];
        #pragma unroll
        for (int a = 0; a < 4; a++){
          acc[a][0] += kv[a]*wv[0]; acc[a][1] += kv[a]*wv[1];
          acc[a][2] += kv[a]*wv[2]; acc[a][3] += kv[a]*wv[3];
        }
      }
    }
    #pragma unroll
    for (int a = 0; a < 4; a++){
      int tl = tq*4 + a;
      #pragma unroll
      for (int c = 0; c < 4; c++){
        int d = dq*4 + c;
        fpre[((size_t)(b*TT + t0 + tl))*DD + d] = acc[a][c] + f_b[d];
      }
    }
  }

  // ---- ypre -> LDS (sK) only; consumed by the fused eapre GEMM below ----
  __syncthreads();   // all sK readers (fpre block) done
  for (int i = tid; i < 32*DD; i += 256){
    int tl = i >> 7, d = i & 127;
    sK[tl*129 + d] =
        a_W[(size_t)d*(NUM_C + DD) + sQ[tl]] * (float)sR[tl] + a_b[d];
  }

  // ---- fused kEA: eapre rows t0..t0+31 (kEA-identical math & layout) ----
  {
    const int jq = tid & 31, rq = tid >> 5;
    for (int jt = 0; jt < 4; jt++){
      __syncthreads();   // prev tile reads done / ypre writes visible
      for (int i = tid; i < 64*128; i += 256){
        int jj = i >> 7, k = i & 127;
        int j = jt*64 + jj;
        u.sW2[jj*129 + k] = (j < 128) ? e_W[(size_t)j*DD + k]
                                      : add_W[(size_t)(j-128)*DD + k];
      }
      __syncthreads();
      float acc[4][2];
      #pragma unroll
      for (int a = 0; a < 4; a++){ acc[a][0] = 0.f; acc[a][1] = 0.f; }
      for (int k = 0; k < 128; k++){
        float fv[4], wv[2];
        #pragma unroll
        for (int a = 0; a < 4; a++) fv[a] = sK[(rq*4 + a)*129 + k];
        wv[0] = u.sW2[(jq*2 + 0)*129 + k];
        wv[1] = u.sW2[(jq*2 + 1)*129 + k];
        #pragma unroll
        for (int a = 0; a < 4; a++){ acc[a][0] += fv[a]*wv[0]; acc[a][1] += fv[a]*wv[1]; }
      }
      #pragma unroll
      for (int a = 0; a < 4; a++){
        int rowi = b*TT + t0 + rq*4 + a;
        #pragma unroll
        for (int c = 0; c < 2; c++){
          int j = jt*64 + jq*2 + c;
          float bj = (j < 128) ? e_b[j] : add_b[j - 128];
          eapre[(size_t)rowi*256 + j] = acc[a][c] + bj;
        }
      }
    }
  }
}

// ---------------------------------------------------------------------------
// Kernel F (R17-verified): 3-role fused pipeline.
//   Blocks  0..31: memory recurrence -> fAll, prog[b]
//   Blocks 32..63: gates GEMM (no prephase)
//   Blocks 64..95: LSTM (LDS key-scan prephase) + kOut tail
// ---------------------------------------------------------------------------
__global__ __launch_bounds__(512, 2) __attribute__((amdgpu_waves_per_eu(2, 2)))
void kFused(
    const float* __restrict__ wAll, const float* __restrict__ fpre,
    const float* __restrict__ eapre, const float* __restrict__ f_W,
    const float* __restrict__ Ge, const float* __restrict__ Ga,
    const float* __restrict__ Mv0, float* __restrict__ fAll,
    const float* __restrict__ Wih4, const float* __restrict__ bih,
    const float* __restrict__ bhh, const ull* __restrict__ keyLo,
    const ull* __restrict__ keyHi,
    const float* __restrict__ Whh, float* __restrict__ Hh,
    float* __restrict__ Ch, float* __restrict__ gpre,
    const float* __restrict__ p_W, const float* __restrict__ p_b,
    float* __restrict__ out, int* __restrict__ prog)
{
  const int tid = threadIdx.x;
  const int b = blockIdx.x & 31;
  const size_t base = (size_t)b*TT;

  __shared__ __align__(16) union SU {
    struct {
      float bufR[144]; float bufF[144]; float sW9[9*52];
      float sF8[8*128]; float sEA8[8*256]; float fO8[8*128];
    } m;
    struct { float sFc[8*128]; } g;
    struct {
      float xh[2][144]; float gbuf[8*512]; int spv[TT];
      float hRing[8*128]; float cRing[8*128]; float pw[DD];
    } l;
  } su;

  if (blockIdx.x < 32){
    // ==================== memory-recurrence role ===========================
    const int dd = tid >> 2, kc = tid & 3, m0 = kc*13;
    const int wslot = (dd >> 5)*36 + (dd & 31);

    float mv[13];
    #pragma unroll
    for (int i = 0; i < 13; i++){
      int m = m0 + i;
      mv[i] = (m < MM) ? Mv0[(size_t)m*DD + dd] : 0.f;
    }
    float wf[32], ge[32], ga[32];
    {
      const float4* p;
      p = reinterpret_cast<const float4*>(&f_W[dd*256 + kc*32]);
      #pragma unroll
      for (int i = 0; i < 8; i++){ float4 v = p[i]; wf[4*i]=v.x; wf[4*i+1]=v.y; wf[4*i+2]=v.z; wf[4*i+3]=v.w; }
      p = reinterpret_cast<const float4*>(&Ge[(size_t)dd*DD + kc*32]);
      #pragma unroll
      for (int i = 0; i < 8; i++){ float4 v = p[i]; ge[4*i]=v.x; ge[4*i+1]=v.y; ge[4*i+2]=v.z; ge[4*i+3]=v.w; }
      p = reinterpret_cast<const float4*>(&Ga[(size_t)dd*DD + kc*32]);
      #pragma unroll
      for (int i = 0; i < 8; i++){ float4 v = p[i]; ga[4*i]=v.x; ga[4*i+1]=v.y; ga[4*i+2]=v.z; ga[4*i+3]=v.w; }
    }

    const int rr0 = tid / 50, mm0 = tid - rr0*50;   // valid when tid < 450
    if (tid < 18){ int rr = tid >> 1; su.m.sW9[rr*52 + 50 + (tid & 1)] = 0.f; }

    float4 pF = {0.f,0.f,0.f,0.f}, pEA = {0.f,0.f,0.f,0.f};
    float pW = 0.f;
    if (tid < 256) pF = reinterpret_cast<const float4*>(&fpre[base*DD])[tid];
    pEA = reinterpret_cast<const float4*>(&eapre[base*256])[tid];
    if (tid < 450) pW = wAll[(base + rr0)*MM + mm0];

    float wreg[13];

    for (int ch = 0; ch < TT/8; ch++){
      const int t0 = ch*8;
      if (ch){
        if (tid < 256){
          float4 v = reinterpret_cast<const float4*>(su.m.fO8)[tid];
          float* dst = &fAll[(base + t0 - 8)*DD + tid*4];
          agStore_(dst+0, v.x); agStore_(dst+1, v.y);
          agStore_(dst+2, v.z); agStore_(dst+3, v.w);
        }
      }
      if (tid < 256) reinterpret_cast<float4*>(su.m.sF8)[tid] = pF;
      reinterpret_cast<float4*>(su.m.sEA8)[tid] = pEA;
      if (tid < 450) su.m.sW9[rr0*52 + mm0] = pW;
      if (ch && tid < 256) waitVM_();     // chunk stores complete before flag
      if (t0 + 8 < TT){
        if (tid < 256) pF = reinterpret_cast<const float4*>(&fpre[(base + t0 + 8)*DD])[tid];
        pEA = reinterpret_cast<const float4*>(&eapre[(base + t0 + 8)*256])[tid];
        if (tid < 450) pW = (t0 + 8 + rr0 < TT) ? wAll[(base + t0 + 8 + rr0)*MM + mm0] : 0.f;
      }
      barL_();   // R: chunk published (and all fAll stores drained)
      if (ch && tid == 0)
        __hip_atomic_store(&prog[b], ch, __ATOMIC_RELAXED, __HIP_MEMORY_SCOPE_AGENT);

      if (ch == 0){
        #pragma unroll
        for (int i = 0; i < 13; i++) wreg[i] = su.m.sW9[m0 + i];
        float r = 0.f;
        #pragma unroll
        for (int i = 0; i < 13; i++) r += wreg[i]*mv[i];
        r = quadSum_(r);
        if (kc == 0) su.m.bufR[wslot] = r;
        barL_();
      }

      #pragma unroll
      for (int tc = 0; tc < 8; tc++){
        float wn[13];
        #pragma unroll
        for (int i = 0; i < 13; i++) wn[i] = su.m.sW9[(tc+1)*52 + m0 + i];

        // ---- stage F: f = tanh(read @ f_Wr.T + fpre) ----
        {
          const float4* x4 = reinterpret_cast<const float4*>(&su.m.bufR[kc*36]);
          float a0=0.f,a1=0.f,a2=0.f,a3=0.f;
          #pragma unroll
          for (int i = 0; i < 8; i++){
            float4 xv = x4[i];
            a0 += xv.x*wf[4*i]; a1 += xv.y*wf[4*i+1]; a2 += xv.z*wf[4*i+2]; a3 += xv.w*wf[4*i+3];
          }
          float s = quadSum_((a0+a1)+(a2+a3));
          float fval = fast_tanh_(s + su.m.sF8[tc*128 + dd]);
          if (kc == 0){
            su.m.bufF[wslot] = fval;
            su.m.fO8[tc*128 + dd] = fval;
          }
        }
        barL_();   // B

        // ---- stage EA: e,a from f; mv update; read_{t+1} = wn . mv_new ----
        {
          const float4* x4 = reinterpret_cast<const float4*>(&su.m.bufF[kc*36]);
          float e0=0.f,e1=0.f,g0=0.f,g1=0.f;
          #pragma unroll
          for (int i = 0; i < 8; i++){
            float4 xv = x4[i];
            e0 += xv.x*ge[4*i];   e1 += xv.y*ge[4*i+1];
            e0 += xv.z*ge[4*i+2]; e1 += xv.w*ge[4*i+3];
            g0 += xv.x*ga[4*i];   g1 += xv.y*ga[4*i+1];
            g0 += xv.z*ga[4*i+2]; g1 += xv.w*ga[4*i+3];
          }
          float ep = quadSum_(e0 + e1);
          float ap = quadSum_(g0 + g1);
          float e_d = fast_sig_(ep + su.m.sEA8[tc*256 + dd]);
          float a_d = fast_tanh_(ap + su.m.sEA8[tc*256 + 128 + dd]);
          float rp0 = 0.f, rp1 = 0.f;
          #pragma unroll
          for (int i = 0; i < 13; i++){
            float t = __builtin_fmaf(-e_d, mv[i], a_d);
            mv[i] = __builtin_fmaf(wreg[i], t, mv[i]);
            if (i & 1) rp1 = __builtin_fmaf(wn[i], mv[i], rp1);
            else       rp0 = __builtin_fmaf(wn[i], mv[i], rp0);
          }
          float rd = quadSum_(rp0 + rp1);
          if (kc == 0) su.m.bufR[wslot] = rd;
        }
        #pragma unroll
        for (int i = 0; i < 13; i++) wreg[i] = wn[i];
        barL_();   // C
      }
    }

    // tail: store last chunk + final flag
    if (tid < 256){
      float4 v = reinterpret_cast<const float4*>(su.m.fO8)[tid];
      float* dst = &fAll[(base + TT - 8)*DD + tid*4];
      agStore_(dst+0, v.x); agStore_(dst+1, v.y);
      agStore_(dst+2, v.z); agStore_(dst+3, v.w);
      waitVM_();
    }
    __syncthreads();
    if (tid == 0)
      __hip_atomic_store(&prog[b], TT/8, __ATOMIC_RELAXED, __HIP_MEMORY_SCOPE_AGENT);

  } else if (blockIdx.x < 64){
    // ==================== gates-GEMM role (no prephase) ====================
    const float biasj = bih[tid] + bhh[tid];   // thread owns gate-column j = tid

    for (int ch = 0; ch < TT/8; ch++){
      const int t0 = ch*8;
      if (tid == 0){
        while (__hip_atomic_load(&prog[b], __ATOMIC_ACQUIRE, __HIP_MEMORY_SCOPE_AGENT) < ch + 1)
          __builtin_amdgcn_s_sleep(2);
      }
      __syncthreads();   // A: join spin; prev chunk's sFc reads/stores done
      if (tid < 256){
        const float* src = &fAll[(base + t0)*DD + tid*4];
        float x0 = agLoad_(src+0), x1 = agLoad_(src+1);
        float x2 = agLoad_(src+2), x3 = agLoad_(src+3);
        su.g.sFc[tid*4+0] = x0; su.g.sFc[tid*4+1] = x1;
        su.g.sFc[tid*4+2] = x2; su.g.sFc[tid*4+3] = x3;
      }
      barL_();           // B: sFc published

      float acc[8];
      #pragma unroll
      for (int uu = 0; uu < 8; uu++) acc[uu] = 0.f;
      for (int k4 = 0; k4 < 32; k4++){
        float4 wv = reinterpret_cast<const float4*>(Wih4)[k4*512 + tid];
        #pragma unroll
        for (int uu = 0; uu < 8; uu++){
          float4 fv = *reinterpret_cast<const float4*>(&su.g.sFc[uu*128 + k4*4]);
          acc[uu] += fv.x*wv.x; acc[uu] += fv.y*wv.y;
          acc[uu] += fv.z*wv.z; acc[uu] += fv.w*wv.w;
        }
      }
      #pragma unroll
      for (int uu = 0; uu < 8; uu++)
        agStore_(&gpre[(base + t0 + uu)*512 + tid], acc[uu] + biasj);
      waitVM_();
      __syncthreads();   // C: all threads' gpre stores drained
      if (tid == 0)
        __hip_atomic_store(&prog[32 + b], ch + 1, __ATOMIC_RELAXED, __HIP_MEMORY_SCOPE_AGENT);
    }

  } else {
    // ==================== LSTM role (scan prephase + kOut tail) ============
    const int jo = tid >> 2, kc = tid & 3;
    const int wslot = (jo >> 5)*36 + (jo & 31);

    float whh[4][32];
    #pragma unroll
    for (int g = 0; g < 4; g++){
      const float4* W4 = reinterpret_cast<const float4*>(&Whh[(size_t)(g*128 + jo)*128 + kc*32]);
      #pragma unroll
      for (int i = 0; i < 8; i++){
        float4 v = W4[i];
        whh[g][4*i] = v.x; whh[g][4*i+1] = v.y; whh[g][4*i+2] = v.z; whh[g][4*i+3] = v.w;
      }
    }

    // --- prephase: key-match scan -> spv (LDS), absorbed into startup idle.
    {
      ull* slo = reinterpret_cast<ull*>(su.l.gbuf);   // 512 ulls (4 KB)
      ull* shi = slo + TT;                            // next 512 ulls
      slo[tid] = keyLo[base + tid];
      shi[tid] = keyHi[base + tid];
      barL_();
      const ull mylo = slo[tid], myhi = shi[tid];
      int found = -1;
      for (int j = tid - 1; j >= 0; j--){
        if (slo[j] == mylo && shi[j] == myhi){ found = j; break; }
      }
      su.l.spv[tid] = found;
      if (tid < DD) su.l.xh[0][(tid >> 5)*36 + (tid & 31)] = 0.f;
      // visibility of spv/xh: first __syncthreads (A) below
    }

    float cin_cur = 0.f;

    for (int ch = 0; ch < TT/8; ch++){
      const int t0 = ch*8;
      if (tid == 0){
        while (__hip_atomic_load(&prog[32 + b], __ATOMIC_ACQUIRE, __HIP_MEMORY_SCOPE_AGENT) < ch + 1)
          __builtin_amdgcn_s_sleep(2);
      }
      __syncthreads();   // A: join spin; prev gbuf reads + Hh/Ch stores done
      // stage gpre chunk (16 KB): thread -> 8 contiguous floats
      {
        const float* src = &gpre[(base + t0)*512 + tid*8];
        float x0 = agLoad_(src+0), x1 = agLoad_(src+1);
        float x2 = agLoad_(src+2), x3 = agLoad_(src+3);
        float x4 = agLoad_(src+4), x5 = agLoad_(src+5);
        float x6 = agLoad_(src+6), x7 = agLoad_(src+7);
        float* d = &su.l.gbuf[tid*8];
        d[0]=x0; d[1]=x1; d[2]=x2; d[3]=x3; d[4]=x4; d[5]=x5; d[6]=x6; d[7]=x7;
      }
      barL_();           // B: gbuf ready (+ ch==0: spv/xh visible)

      #pragma unroll
      for (int tc = 0; tc < 8; tc++){
        const int t = t0 + tc, p = t & 1;
        if (tc) barL_();                 // xh[p] + ring ready

        int pv2 = -1; float preH = 0.f, preC = 0.f;
        if (t + 1 < TT){
          pv2 = su.l.spv[t + 1];
          if (pv2 >= 0 && pv2 < t){
            if (pv2 >= t0){              // in-chunk: LDS ring
              preH = su.l.hRing[(pv2 & 7)*128 + jo];
              preC = su.l.cRing[(pv2 & 7)*128 + jo];
            } else {                     // older chunk: global (same block wrote it)
              preH = Hh[(base + pv2)*DD + jo];
              preC = Ch[(base + pv2)*DD + jo];
            }
          }
        }

        float gp0 = su.l.gbuf[tc*512 + jo];
        float gp1 = su.l.gbuf[tc*512 + 128 + jo];
        float gp2 = su.l.gbuf[tc*512 + 256 + jo];
        float gp3 = su.l.gbuf[tc*512 + 384 + jo];

        float a0=0.f,a1=0.f,a2=0.f,a3=0.f;
        {
          const float4* x4 = reinterpret_cast<const float4*>(&su.l.xh[p][kc*36]);
          #pragma unroll
          for (int i = 0; i < 8; i++){
            float4 xv = x4[i];
            a0 += xv.x*whh[0][4*i]; a0 += xv.y*whh[0][4*i+1]; a0 += xv.z*whh[0][4*i+2]; a0 += xv.w*whh[0][4*i+3];
            a1 += xv.x*whh[1][4*i]; a1 += xv.y*whh[1][4*i+1]; a1 += xv.z*whh[1][4*i+2]; a1 += xv.w*whh[1][4*i+3];
            a2 += xv.x*whh[2][4*i]; a2 += xv.y*whh[2][4*i+1]; a2 += xv.z*whh[2][4*i+2]; a2 += xv.w*whh[2][4*i+3];
            a3 += xv.x*whh[3][4*i]; a3 += xv.y*whh[3][4*i+1]; a3 += xv.z*whh[3][4*i+2]; a3 += xv.w*whh[3][4*i+3];
          }
        }
        a0 = quadSum_(a0); a1 = quadSum_(a1); a2 = quadSum_(a2); a3 = quadSum_(a3);

        const float ig = gp0 + a0, fg = gp1 + a1, gg = gp2 + a2, og = gp3 + a3;
        const float cn = fast_sig_(fg)*cin_cur + fast_sig_(ig)*fast_tanh_(gg);
        const float hn = fast_sig_(og)*fast_tanh_(cn);

        if (kc == 0){
          Hh[(base + t)*DD + jo] = hn;
          Ch[(base + t)*DD + jo] = cn;
          su.l.hRing[(t & 7)*128 + jo] = hn;
          su.l.cRing[(t & 7)*128 + jo] = cn;
        }

        float hin_n, cin_n;
        if (pv2 < 0 || pv2 >= t){ hin_n = hn; cin_n = cn; }       // carry
        else                     { hin_n = preH; cin_n = preC; }   // skip
        if (kc == 0) su.l.xh[1 - p][wslot] = hin_n;
        cin_cur = cin_n;
      }
    }

    // ---- tail: output head for this batch (bit-identical to kOut) ----
    __syncthreads();                       // drains this block's Hh stores
    if (tid < DD) su.l.pw[tid] = p_W[tid];
    barL_();
    {
      const int t = tid;
      const float* hrow = &Hh[(base + t)*DD];
      float s = 0.f;
      #pragma unroll
      for (int k4 = 0; k4 < 32; k4++){
        float4 hv = *reinterpret_cast<const float4*>(&hrow[k4*4]);
        const float* wp = &su.l.pw[k4*4];
        s += hv.x*wp[0] + hv.y*wp[1] + hv.z*wp[2] + hv.w*wp[3];
      }
      out[base + t] = sigmoidf_(s + p_b[0]);
    }
  }
}

// ---------------------------------------------------------------------------
// Launch.
// ---------------------------------------------------------------------------
extern "C" void kernel_launch(void* const* d_in, const int* in_sizes, int n_in,
                              void* d_out, int out_size, void* d_ws, size_t ws_size,
                              hipStream_t stream) {
  const int*   q     = (const int*)  d_in[0];
  const int*   r     = (const int*)  d_in[1];
  const float* k_emb = (const float*)d_in[2];
  const float* Mk    = (const float*)d_in[3];
  const float* Mv0   = (const float*)d_in[4];
  const float* f_W   = (const float*)d_in[5];
  const float* f_b   = (const float*)d_in[6];
  const float* a_W   = (const float*)d_in[7];
  const float* a_b   = (const float*)d_in[8];
  const float* e_W   = (const float*)d_in[9];
  const float* e_b   = (const float*)d_in[10];
  const float* add_W = (const float*)d_in[11];
  const float* add_b = (const float*)d_in[12];
  const float* Wih   = (const float*)d_in[13];
  const float* Whh   = (const float*)d_in[14];
  const float* bih   = (const float*)d_in[15];
  const float* bhh   = (const float*)d_in[16];
  const float* p_W   = (const float*)d_in[17];
  const float* p_b   = (const float*)d_in[18];
  float* out = (float*)d_out;

  char* ws = (char*)d_ws;
  size_t off = 0;
  auto alloc = [&](size_t bytes) -> char* {
    char* p = ws + off;
    off += (bytes + 255) & ~(size_t)255;
    return p;
  };
  float* wAll  = (float*)alloc((size_t)BB*TT*MM*4);
  float* fpre  = (float*)alloc((size_t)BB*TT*DD*4);
  float* fAll  = (float*)alloc((size_t)BB*TT*DD*4);
  float* eapre = (float*)alloc((size_t)BB*TT*256*4);
  float* gpre  = (float*)alloc((size_t)BB*TT*512*4);
  float* Hh    = (float*)alloc((size_t)BB*TT*DD*4);
  float* Ch    = (float*)alloc((size_t)BB*TT*DD*4);
  ull*   keyLo = (ull*)  alloc((size_t)BB*TT*8);
  ull*   keyHi = (ull*)  alloc((size_t)BB*TT*8);
  float* Ge    = (float*)alloc((size_t)DD*DD*4);
  float* Ga    = (float*)alloc((size_t)DD*DD*4);
  float* Wih4  = (float*)alloc((size_t)512*DD*4);
  int*   prog  = (int*)  alloc(512);
  (void)ws_size; (void)in_sizes; (void)n_in; (void)out_size;

  kPre  <<<dim3(16, 33), 256, 0, stream>>>(q, r, k_emb, Mk, f_W, f_b, a_W, a_b,
                                           wAll, keyLo, keyHi, fpre,
                                           e_W, add_W, e_b, add_b, eapre,
                                           Ge, Ga, Wih, Wih4, prog);
  kFused<<<96, 512, 0, stream>>>(wAll, fpre, eapre, f_W, Ge, Ga, Mv0, fAll,
                                 Wih4, bih, bhh, keyLo, keyHi, Whh,
                                 Hh, Ch, gpre, p_W, p_b, out, prog);
}